// Round 11
// baseline (179.973 us; speedup 1.0000x reference)
//
#include <hip/hip_runtime.h>

#define T_LEN 120000
#define LBLK 64           // scan block length
#define PBLK 1875         // scan blocks (64*1875 = 120000)
#define SEG_LEN 25        // blocks per scan segment
#define NSEG 75           // segments
#define BATCH 4
#define M0 625            // first valid 64-block (t = 40000)
#define NMB 625           // valid 64-blocks
#define DENOM 20480000.0  // 2 * 4 * 64 * 40000
#define NSLOT 128
#define YSTRB 160         // Byh col stride in halves (320 B, 2-way-free banks)
#define SCL 256.0         // taps scale (A side *SCL, x side /SCL) vs f16 subnormals

typedef _Float16 half8 __attribute__((ext_vector_type(8)));
typedef float f32x4 __attribute__((ext_vector_type(4)));

__device__ __forceinline__ float fast_tanh(float x) {
  float e = __expf(2.0f * x);
  return 1.0f - 2.0f / (e + 1.0f);
}

// Harness may store the reference's float64 arrays as f64 or f32.
__device__ __forceinline__ bool coeffs_are_f64(const void* a2p) {
  double probe = *(const double*)a2p;
  return probe > 0.9 && probe < 1.0;
}
__device__ __forceinline__ double coeff_d(const void* p, bool f64, int ch) {
  return f64 ? ((const double*)p)[ch] : (double)((const float*)p)[ch];
}

// A^e for A = [[-a1,-a2],[1,0]] by repeated squaring (f64)
__device__ __forceinline__ void mat_pow(double A1, double A2, int e,
                                        double& r00, double& r01,
                                        double& r10, double& r11) {
  double m00 = -A1, m01 = -A2, m10 = 1.0, m11 = 0.0;
  r00 = 1.0; r01 = 0.0; r10 = 0.0; r11 = 1.0;
  while (e) {
    if (e & 1) {
      double t00 = r00 * m00 + r01 * m10, t01 = r00 * m01 + r01 * m11;
      double t10 = r10 * m00 + r11 * m10, t11 = r10 * m01 + r11 * m11;
      r00 = t00; r01 = t01; r10 = t10; r11 = t11;
    }
    e >>= 1;
    if (e) {
      double t00 = m00 * m00 + m01 * m10, t01 = m00 * m01 + m01 * m11;
      double t10 = m10 * m00 + m11 * m10, t11 = m10 * m01 + m11 * m11;
      m00 = t00; m01 = t01; m10 = t10; m11 = t11;
    }
  }
}

// setupA: per-channel impulse response h[0..63], homogeneous tables g1/g2,
// H2 (pass1 taps, x SCL), Gtab (f32, d-flip baked), zero wsum. 64 threads.
__global__ __launch_bounds__(64) void setupA(
    const void* a1p, const void* a2p, const void* b0p,
    float* __restrict__ h32, float2* __restrict__ Gtab,
    _Float16* __restrict__ H2, double* __restrict__ wsum)
{
  int ch = threadIdx.x;
  wsum[ch] = 0.0; wsum[64 + ch] = 0.0;
  bool f64 = coeffs_are_f64(a2p);
  double A1 = coeff_d(a1p, f64, ch), A2 = coeff_d(a2p, f64, ch);
  double B0 = coeff_d(b0p, f64, ch);
  // h recurrence (streamed)
  double h1 = 0.0, h2v = 0.0;  // h[j-1], h[j-2]
  for (int j = 0; j < 64; ++j) {
    double h = (j == 0) ? B0 : (-A1 * h1 - A2 * h2v);
    h32[ch * 64 + j] = (float)h;
    H2[(ch)*64 + j] = (_Float16)(h * SCL);
    H2[(64 + ch) * 64 + j] = (_Float16)(h1 * SCL);  // h[j-1], 0 at j=0
    h2v = h1; h1 = h;
  }
  // g1: homog from (y[-1],y[-2]) = (1,0); g2: from (0,1)
  double a_1 = 1.0, a_2 = 0.0, b_1 = 0.0, b_2 = 1.0;
  for (int tt = 0; tt < 64; ++tt) {
    double g1 = -A1 * a_1 - A2 * a_2;
    double g2 = -A1 * b_1 - A2 * b_2;
    Gtab[tt * 128 + ch] = make_float2((float)g1, (float)g2);          // d=0
    Gtab[(63 - tt) * 128 + 64 + ch] = make_float2((float)g1, (float)g2); // d=1
    a_2 = a_1; a_1 = g1; b_2 = b_1; b_1 = g2;
  }
}

// setupB: A-matrix [W@Hf*SCL | W@Hb*SCL | W] as f16 [64][256]. grid 4 x 256.
__global__ __launch_bounds__(256) void setupB(
    const float* __restrict__ h32, const float* __restrict__ W,
    _Float16* __restrict__ Ag)
{
  __shared__ float hs[64 * 64];   // hs[j*64 + ch] (transposed)
  int tid = threadIdx.x;
  for (int idx = tid; idx < 4096; idx += 256) {
    int ch = idx >> 6, j = idx & 63;
    hs[j * 64 + ch] = h32[idx];
  }
  __syncthreads();
  int ol = tid >> 4, jq = tid & 15;
  int o = blockIdx.x * 16 + ol;
  #pragma unroll
  for (int q = 0; q < 4; ++q) {
    int j = jq + q * 16;
    float whf = 0.f, whb = 0.f;
    for (int ch = 0; ch < 64; ++ch) {
      float h = hs[j * 64 + ch];
      whf = fmaf(W[o * 128 + ch], h, whf);
      whb = fmaf(W[o * 128 + 64 + ch], h, whb);
    }
    Ag[o * 256 + j] = (_Float16)(whf * (float)SCL);
    Ag[o * 256 + 64 + j] = (_Float16)(whb * (float)SCL);
  }
  for (int e = tid; e < 2048; e += 256) {
    int ol2 = e >> 7, c = e & 127;
    int oo = blockIdx.x * 16 + ol2;
    Ag[oo * 256 + 128 + c] = (_Float16)W[oo * 128 + c];
  }
}

// pass1: block-end states via Toeplitz MFMA. C[(pair,ch)][block] =
// sum_j H2[(pair,ch)][j] * xs_r[64*block + 63 - j]. grid (30, 16) x 256.
__global__ __launch_bounds__(256) void pass1(
    const float* __restrict__ pred, const float* __restrict__ tgt,
    const _Float16* __restrict__ H2, float* __restrict__ fbuf)
{
  __shared__ _Float16 revP[64 * 96];  // [block-local][64 rev samples + pad]
  int tid = threadIdx.x;
  int bx = blockIdx.x, r = blockIdx.y;
  int i = r >> 3, d = (r >> 2) & 1;
  int b = r & 3;
  const float* sig = (i ? tgt : pred) + b * T_LEN;
  int base = bx * 4096;
  for (int e = tid; e < 4096; e += 256) {
    int blk = e >> 6, m = e & 63;
    int src = base + (blk << 6) + 63 - m;
    if (src > T_LEN - 1) src = T_LEN - 1;
    float x = d ? sig[T_LEN - 1 - src] : sig[src];
    revP[blk * 96 + m] = (_Float16)(x * (float)(1.0 / SCL));
  }
  __syncthreads();

  int g = tid >> 6, lane = tid & 63;
  int gu = __builtin_amdgcn_readfirstlane(g);
  int lm = lane & 15, quad = lane >> 4;
  int nt = gu * 16;            // wave's 16 blocks
  int nl = nt + lm;            // lane's block (local)

  f32x4 acc[8];
  #pragma unroll
  for (int mt = 0; mt < 8; ++mt) acc[mt] = (f32x4){0.f, 0.f, 0.f, 0.f};
  #pragma unroll
  for (int k0 = 0; k0 < 2; ++k0) {
    half8 bf = *(const half8*)&revP[nl * 96 + 32 * k0 + 8 * quad];
    #pragma unroll
    for (int mt = 0; mt < 8; ++mt) {
      half8 af = *(const half8*)&H2[(mt * 16 + lm) * 64 + 32 * k0 + 8 * quad];
      acc[mt] = __builtin_amdgcn_mfma_f32_16x16x32_f16(af, bf, acc[mt], 0, 0, 0);
    }
  }
  int n = bx * 64 + nl;
  if (n < PBLK) {
    #pragma unroll
    for (int mt = 0; mt < 8; ++mt) {
      #pragma unroll
      for (int reg = 0; reg < 4; ++reg) {
        int mr = mt * 16 + quad * 4 + reg;
        int ch = mr & 63, pair = mr >> 6;
        fbuf[((size_t)n * 1024 + r * 64 + ch) * 2 + pair] = acc[mt][reg];
      }
    }
  }
}

// pass2a: per-segment aggregate (25 blocks, zero init), f64. grid 75*16 x 64.
__global__ __launch_bounds__(64) void pass2a(
    const void* a1p, const void* a2p,
    const float2* __restrict__ fbuf, double* __restrict__ sbuf)
{
  int seg = blockIdx.x >> 4;
  int s = ((blockIdx.x & 15) << 6) + threadIdx.x;
  int ch = s & 63;
  bool f64 = coeffs_are_f64(a2p);
  double r00, r01, r10, r11;
  mat_pow(coeff_d(a1p, f64, ch), coeff_d(a2p, f64, ch), LBLK, r00, r01, r10, r11);
  double y1 = 0.0, y2 = 0.0;
  #pragma unroll 1
  for (int jj = 0; jj < SEG_LEN / 5; ++jj) {
    size_t kb = (size_t)(seg * SEG_LEN + jj * 5) * 1024 + s;
    float2 f0 = fbuf[kb], f1 = fbuf[kb + 1024], f2 = fbuf[kb + 2048],
           f3 = fbuf[kb + 3072], f4 = fbuf[kb + 4096];
    double n1, n2;
    n1 = r00*y1 + r01*y2 + (double)f0.x; n2 = r10*y1 + r11*y2 + (double)f0.y; y1=n1; y2=n2;
    n1 = r00*y1 + r01*y2 + (double)f1.x; n2 = r10*y1 + r11*y2 + (double)f1.y; y1=n1; y2=n2;
    n1 = r00*y1 + r01*y2 + (double)f2.x; n2 = r10*y1 + r11*y2 + (double)f2.y; y1=n1; y2=n2;
    n1 = r00*y1 + r01*y2 + (double)f3.x; n2 = r10*y1 + r11*y2 + (double)f3.y; y1=n1; y2=n2;
    n1 = r00*y1 + r01*y2 + (double)f4.x; n2 = r10*y1 + r11*y2 + (double)f4.y; y1=n1; y2=n2;
  }
  ((double2*)sbuf)[(size_t)seg * 1024 + s] = make_double2(y1, y2);
}

// pass2b: serial scan over 75 segment aggregates -> segment-start states.
__global__ __launch_bounds__(256) void pass2b(
    const void* a1p, const void* a2p,
    const double* __restrict__ sbuf, double* __restrict__ tbuf)
{
  int s = blockIdx.x * 256 + threadIdx.x;
  int ch = s & 63;
  bool f64 = coeffs_are_f64(a2p);
  double r00, r01, r10, r11;
  mat_pow(coeff_d(a1p, f64, ch), coeff_d(a2p, f64, ch), LBLK * SEG_LEN,
          r00, r01, r10, r11);
  const double2* sb = (const double2*)sbuf;
  double2* tb = (double2*)tbuf;
  double y1 = 0.0, y2 = 0.0;
  #pragma unroll 1
  for (int bb = 0; bb < NSEG; bb += 15) {
    double2 f[15];
    #pragma unroll
    for (int q = 0; q < 15; ++q) f[q] = sb[(size_t)(bb + q) * 1024 + s];
    #pragma unroll
    for (int q = 0; q < 15; ++q) {
      tb[(size_t)(bb + q) * 1024 + s] = make_double2(y1, y2);
      double n1 = r00 * y1 + r01 * y2 + f[q].x;
      double n2 = r10 * y1 + r11 * y2 + f[q].y;
      y1 = n1; y2 = n2;
    }
  }
}

// pass2c: expand segments 25..49 -> jbuf block states m in [625,1249] (f32).
__global__ __launch_bounds__(64) void pass2c(
    const void* a1p, const void* a2p,
    const float2* __restrict__ fbuf, const double* __restrict__ tbuf,
    float2* __restrict__ jbuf)
{
  int seg = 25 + blockIdx.x;
  int r = blockIdx.y;
  int ch = threadIdx.x;
  int s = r * 64 + ch;
  bool f64 = coeffs_are_f64(a2p);
  double r00, r01, r10, r11;
  mat_pow(coeff_d(a1p, f64, ch), coeff_d(a2p, f64, ch), LBLK, r00, r01, r10, r11);
  double2 v = ((const double2*)tbuf)[(size_t)seg * 1024 + s];
  double y1 = v.x, y2 = v.y;
  #pragma unroll 1
  for (int jj = 0; jj < SEG_LEN / 5; ++jj) {
    float2 f[5];
    #pragma unroll
    for (int q = 0; q < 5; ++q)
      f[q] = fbuf[(size_t)(seg * SEG_LEN + jj * 5 + q) * 1024 + s];
    #pragma unroll
    for (int q = 0; q < 5; ++q) {
      int m = seg * SEG_LEN + jj * 5 + q;
      jbuf[(size_t)(m - M0) * 1024 + s] = make_float2((float)y1, (float)y2);
      double n1 = r00 * y1 + r01 * y2 + (double)f[q].x;
      double n2 = r10 * y1 + r11 * y2 + (double)f[q].y;
      y1 = n1; y2 = n2;
    }
  }
}

// pass3: recurrence-free. Per (64-t block mb, batch b):
//   z = [WHf|WHb|W] @ [Xf_toeplitz ; Xb_toeplitz ; yh]  (K=256, N=128 cols)
// cols n = 2*tt + i. Taps read from padded stages P/Q (masks = zero pads);
// yh = st0*g1 + st1*g2 built in f32 -> f16 LDS. tanh + |p-t| via shfl_xor(1).
__global__ __launch_bounds__(256, 3) void pass3(
    const float* __restrict__ pred, const float* __restrict__ tgt,
    const _Float16* __restrict__ Ag, const float2* __restrict__ Gtab,
    const float2* __restrict__ jbuf, double* __restrict__ wsum)
{
  __shared__ _Float16 Byh[128 * YSTRB];
  __shared__ _Float16 P[2][128], Q[2][128];
  __shared__ float2 sts[2][2][64];
  __shared__ float red[4];

  int mb = M0 + blockIdx.x;
  int b = blockIdx.y;
  int tid = threadIdx.x;
  int t0 = mb * 64;

  // stage taps windows (scaled 1/SCL; zero pads implement the masks)
  {
    int idx = tid & 127, ii = tid >> 7;
    const float* xi = (ii ? tgt : pred) + b * T_LEN + t0;
    _Float16 pv = (idx < 64) ? (_Float16)(xi[63 - idx] * (float)(1.0 / SCL))
                             : (_Float16)0.f;
    _Float16 qv = (idx < 64) ? (_Float16)(xi[idx] * (float)(1.0 / SCL))
                             : (_Float16)0.f;
    P[ii][idx] = pv;
    Q[ii][idx] = qv;
  }
  // stage states
  {
    int ii = tid >> 7, dd = (tid >> 6) & 1, ch = tid & 63;
    int r = ii * 8 + dd * 4 + b;
    int jidx = dd ? (1249 - mb) : (mb - M0);
    sts[ii][dd][ch] = jbuf[(size_t)jidx * 1024 + r * 64 + ch];
  }
  __syncthreads();

  // yh build: thread = (col n, half h2 of ch2-range)
  {
    int n = tid & 127, h2 = tid >> 7;
    int ii = n & 1, tt = n >> 1;
    const float2* gp = Gtab + tt * 128 + h2 * 64;
    #pragma unroll
    for (int c8 = 0; c8 < 8; ++c8) {
      half8 hv;
      #pragma unroll
      for (int e = 0; e < 8; ++e) {
        int ch = c8 * 8 + e;
        float2 gg = gp[ch];
        float2 ss = sts[ii][h2][ch];
        hv[e] = (_Float16)(ss.x * gg.x + ss.y * gg.y);
      }
      *(half8*)&Byh[n * YSTRB + h2 * 64 + c8 * 8] = hv;
    }
  }
  __syncthreads();

  int g = tid >> 6, lane = tid & 63;
  int gu = __builtin_amdgcn_readfirstlane(g);
  int lm = lane & 15, quad = lane >> 4;

  f32x4 acc[2][4];
  #pragma unroll
  for (int a = 0; a < 2; ++a)
    #pragma unroll
    for (int m0 = 0; m0 < 4; ++m0) acc[a][m0] = (f32x4){0.f, 0.f, 0.f, 0.f};

  #pragma unroll
  for (int k0 = 0; k0 < 8; ++k0) {
    half8 bf[2];
    #pragma unroll
    for (int nti = 0; nti < 2; ++nti) {
      int n = gu * 32 + nti * 16 + lm;
      int ii = n & 1, tt = n >> 1;
      if (k0 < 2) {
        const _Float16* pp = &P[ii][63 - tt + 32 * k0 + 8 * quad];
        #pragma unroll
        for (int j = 0; j < 8; ++j) bf[nti][j] = pp[j];
      } else if (k0 < 4) {
        const _Float16* qq = &Q[ii][tt + 32 * (k0 - 2) + 8 * quad];
        #pragma unroll
        for (int j = 0; j < 8; ++j) bf[nti][j] = qq[j];
      } else {
        bf[nti] = *(const half8*)&Byh[n * YSTRB + 32 * (k0 - 4) + 8 * quad];
      }
    }
    #pragma unroll
    for (int m0 = 0; m0 < 4; ++m0) {
      half8 af = *(const half8*)&Ag[(m0 * 16 + lm) * 256 + 32 * k0 + 8 * quad];
      acc[0][m0] = __builtin_amdgcn_mfma_f32_16x16x32_f16(af, bf[0], acc[0][m0], 0, 0, 0);
      acc[1][m0] = __builtin_amdgcn_mfma_f32_16x16x32_f16(af, bf[1], acc[1][m0], 0, 0, 0);
    }
  }

  float loss = 0.0f;
  #pragma unroll
  for (int nti = 0; nti < 2; ++nti)
    #pragma unroll
    for (int m0 = 0; m0 < 4; ++m0)
      #pragma unroll
      for (int reg = 0; reg < 4; ++reg) {
        float vv = fast_tanh(acc[nti][m0][reg]);
        float p = __shfl_xor(vv, 1);
        loss += fabsf(vv - p);
      }

  #pragma unroll
  for (int off = 32; off > 0; off >>= 1) loss += __shfl_down(loss, off);
  if ((tid & 63) == 0) red[tid >> 6] = loss;
  __syncthreads();
  if (tid == 0) {
    int slot = (blockIdx.x * 4 + blockIdx.y) & (NSLOT - 1);
    atomicAdd(&wsum[slot], (double)(red[0] + red[1] + red[2] + red[3]));
  }
}

__global__ __launch_bounds__(128) void finalize(
    const double* __restrict__ wsum, float* __restrict__ out) {
  __shared__ double part[2];
  int tid = threadIdx.x;
  double v = wsum[tid];
  #pragma unroll
  for (int off = 32; off > 0; off >>= 1) v += __shfl_down(v, off);
  if ((tid & 63) == 0) part[tid >> 6] = v;
  __syncthreads();
  if (tid == 0) out[0] = (float)((part[0] + part[1]) / DENOM);
}

extern "C" void kernel_launch(void* const* d_in, const int* in_sizes, int n_in,
                              void* d_out, int out_size, void* d_ws, size_t ws_size,
                              hipStream_t stream) {
  const float* pred = (const float*)d_in[0];
  const float* tgt  = (const float*)d_in[1];
  const void* a1p = d_in[2];
  const void* a2p = d_in[3];
  const void* b0p = d_in[4];
  const float* W  = (const float*)d_in[5];
  float* out = (float*)d_out;

  char* base = (char*)d_ws;
  double*   wsum = (double*)(base + 0);               // 128 f64 (1 KB)
  float*    h32  = (float*)(base + 1024);             // [64][64] (16 KB)
  float2*   Gtab = (float2*)(base + 17408);           // [64][128] (64 KB)
  _Float16* H2   = (_Float16*)(base + 82944);         // [128][64] (16 KB)
  _Float16* Ag   = (_Float16*)(base + 99328);         // [64][256] (32 KB)
  float2*   fbuf = (float2*)(base + 132096);          // [1875][1024] (15.36 MB)
  double*   sbuf = (double*)(base + 15492096);        // [75][1024][2] f64
  double*   tbuf = (double*)(base + 16720896);        // [75][1024][2] f64
  float2*   jbuf = (float2*)(base + 17949696);        // [625][1024] (5.12 MB)

  setupA<<<1, 64, 0, stream>>>(a1p, a2p, b0p, h32, Gtab, H2, wsum);
  setupB<<<4, 256, 0, stream>>>(h32, W, Ag);
  pass1<<<dim3(30, 16), 256, 0, stream>>>(pred, tgt, H2, (float*)fbuf);
  pass2a<<<NSEG * 16, 64, 0, stream>>>(a1p, a2p, fbuf, sbuf);
  pass2b<<<4, 256, 0, stream>>>(a1p, a2p, sbuf, tbuf);
  pass2c<<<dim3(25, 16), 64, 0, stream>>>(a1p, a2p, fbuf, tbuf, jbuf);
  pass3<<<dim3(NMB, BATCH), 256, 0, stream>>>(pred, tgt, Ag, Gtab, jbuf, wsum);
  finalize<<<1, 128, 0, stream>>>(wsum, out);
}